// Round 8
// baseline (1619.156 us; speedup 1.0000x reference)
//
#include <hip/hip_runtime.h>
#include <math.h>

#define DEVFN __device__ __forceinline__

namespace {

typedef __bf16 bf16x8 __attribute__((ext_vector_type(8)));
typedef float  f32x4  __attribute__((ext_vector_type(4)));

constexpr int T = 28, B = 16384, X = 28, H = 100, Z = 16;
constexpr int ROWS = 16;           // single M-tile per block -> grid 1024 -> up to 4 blocks/CU (grid no longer caps)
constexpr int NTH  = 256;          // 4 waves/block
constexpr int ST   = 104;          // bf16 LDS stride; col 100 = bias-one, 101+ zero
constexpr int HBUF = ROWS*ST + 24; // tail pad: row-15 kc=3 frag overrun stays in-buffer (zeroed)
constexpr int XST  = 40;           // stride for Z rows
constexpr float KEPS = 1e-10f;

// ---- weight-fragment table (1 frag = 16x32 B-tile = 64 lanes x 16B = 1024B) ----
constexpr int FB_PX   = 0;    // 7   KT=1
constexpr int FB_HE   = 7;    // 56  KT=8 (concat px|h)
constexpr int FB_EMU  = 63;   // 4   KT=4
constexpr int FB_ESIG = 67;   // 4
constexpr int FB_HP   = 71;   // 28  KT=4
constexpr int FB_PMU  = 99;   // 4
constexpr int FB_PSIG = 103;  // 4
constexpr int FB_PZ   = 107;  // 7   KT=1
constexpr int FB_HD1  = 114;  // 56  KT=8 (concat pz|h)
constexpr int FB_HD2  = 170;  // 28  KT=4
constexpr int FB_PRB  = 198;  // 8   KT=4 (Nt=2)
constexpr int FB_GIR  = 206;  // 56  KT=8 (concat pz|px)
constexpr int FB_GIU  = 262;  // 56
constexpr int FB_GIN  = 318;  // 56
constexpr int FB_GHR  = 374;  // 28  KT=4
constexpr int FB_GHU  = 402;  // 28
constexpr int FB_GHN  = 430;  // 28
constexpr int NFRAG   = 458;  // 469 KB in d_ws

struct Params {
  const float *x,*eps,*Wpx,*bpx,*Wpz,*bpz,*Wp1,*bp1,*Wp_mu,*bp_mu,*Wp_sig,*bp_sig,
              *We1,*be1,*We_mu,*be_mu,*We_sig,*be_sig,*Wd1,*bd1,*Wd2,*bd2,*Wd3,*bd3,
              *Wih,*Whh,*bih,*bhh;
  float *out;
};

DEVFN float frcp(float x){ return __builtin_amdgcn_rcpf(x); }
DEVFN float fsigmoid(float v){ return frcp(1.f + __expf(-v)); }
DEVFN float ftanh(float v){
  float t = __expf(-2.f*fabsf(v));           // (0,1], no overflow
  float r = (1.f - t) * frcp(1.f + t);
  return copysignf(r, v);
}
DEVFN float fsoftplus(float v){
  float sp = (v > 15.f) ? v : __logf(1.f + __expf(v));
  return fmaxf(sp, 1e-6f);                   // log/rcp safety in KL tail
}

DEVFN f32x4 MFMA(bf16x8 a, bf16x8 b, f32x4 c){
  return __builtin_amdgcn_mfma_f32_16x16x32_bf16(a, b, c, 0, 0, 0);
}

// ---------------- weight prep: fp32 -> bf16 B-fragments, biases folded into K-pad slot ----------------
__global__ void prep_kernel(Params P, __bf16* FRW)
{
  const int f = blockIdx.x, l = threadIdx.x;
  const int bases[18] = {FB_PX,FB_HE,FB_EMU,FB_ESIG,FB_HP,FB_PMU,FB_PSIG,FB_PZ,FB_HD1,
                         FB_HD2,FB_PRB,FB_GIR,FB_GIU,FB_GIN,FB_GHR,FB_GHU,FB_GHN,NFRAG};
  int li = 0;
  while (f >= bases[li+1]) ++li;

  const float* W; const float* Bv; int KT, N, roff, wstr, vK, mode;
  switch (li) {
    case 0:  W=P.Wpx;    Bv=P.bpx;    KT=1; N=100; roff=0;   wstr=28;  vK=28;  mode=0; break;
    case 1:  W=P.We1;    Bv=P.be1;    KT=8; N=100; roff=0;   wstr=200; vK=100; mode=1; break;
    case 2:  W=P.We_mu;  Bv=P.be_mu;  KT=4; N=16;  roff=0;   wstr=100; vK=100; mode=0; break;
    case 3:  W=P.We_sig; Bv=P.be_sig; KT=4; N=16;  roff=0;   wstr=100; vK=100; mode=0; break;
    case 4:  W=P.Wp1;    Bv=P.bp1;    KT=4; N=100; roff=0;   wstr=100; vK=100; mode=0; break;
    case 5:  W=P.Wp_mu;  Bv=P.bp_mu;  KT=4; N=16;  roff=0;   wstr=100; vK=100; mode=0; break;
    case 6:  W=P.Wp_sig; Bv=P.bp_sig; KT=4; N=16;  roff=0;   wstr=100; vK=100; mode=0; break;
    case 7:  W=P.Wpz;    Bv=P.bpz;    KT=1; N=100; roff=0;   wstr=16;  vK=16;  mode=0; break;
    case 8:  W=P.Wd1;    Bv=P.bd1;    KT=8; N=100; roff=0;   wstr=200; vK=100; mode=1; break;
    case 9:  W=P.Wd2;    Bv=P.bd2;    KT=4; N=100; roff=0;   wstr=100; vK=100; mode=0; break;
    case 10: W=P.Wd3;    Bv=P.bd3;    KT=4; N=28;  roff=0;   wstr=100; vK=100; mode=0; break;
    case 11: W=P.Wih;    Bv=P.bih;    KT=8; N=100; roff=0;   wstr=200; vK=100; mode=1; break;
    case 12: W=P.Wih;    Bv=P.bih;    KT=8; N=100; roff=100; wstr=200; vK=100; mode=1; break;
    case 13: W=P.Wih;    Bv=P.bih;    KT=8; N=100; roff=200; wstr=200; vK=100; mode=1; break;
    case 14: W=P.Whh;    Bv=P.bhh;    KT=4; N=100; roff=0;   wstr=100; vK=100; mode=0; break;
    case 15: W=P.Whh;    Bv=P.bhh;    KT=4; N=100; roff=100; wstr=100; vK=100; mode=0; break;
    default: W=P.Whh;    Bv=P.bhh;    KT=4; N=100; roff=200; wstr=100; vK=100; mode=0; break;
  }
  const int idx = f - bases[li];
  const int nt = idx / KT, kc = idx % KT;
  const int n  = nt*16 + (l & 15);

  bf16x8 v;
  #pragma unroll
  for (int j = 0; j < 8; ++j) {
    int kk  = (mode ? (kc & 3) : kc)*32 + ((l >> 4)*8) + j;
    float w = 0.f;
    if (n < N) {
      if (mode == 0) {
        if (kk < vK)       w = W[(size_t)(roff + n)*wstr + kk];
        else if (kk == vK) w = Bv[roff + n];                      // bias in K-pad slot
      } else {
        int col = (kc < 4 ? 0 : 100) + kk;
        if (kk < 100)                    w = W[(size_t)(roff + n)*wstr + col];
        else if (kc < 4 && kk == 100)    w = Bv[roff + n];        // bias in segment-0 pad slot
      }
    }
    v[j] = (__bf16)w;
  }
  *((bf16x8*)FRW + (size_t)f*64 + l) = v;
}

// ---------------- main kernel helpers (single M-tile, 4-wave round-robin N-tile split) ----------------
template<int NC>
DEVFN void load_afrags(bf16x8 (&af)[NC], const __bf16* A, int stride, int lane)
{
  const __bf16* p = A + (size_t)(lane & 15)*stride + ((lane >> 4)*8);
  #pragma unroll
  for (int kc = 0; kc < NC; ++kc) af[kc] = *(const bf16x8*)(p + kc*32);
}

// H-output layer: this wave does nt = sw, sw+step, ... ; relu; bias pre-folded into weights
template<int KT, int NA>
DEVFN void layerH(const bf16x8 (&af)[NA], const bf16x8* FRbase, __bf16* dst, int sw, int step, int lane)
{
  for (int nt = sw; nt < 7; nt += step) {
    f32x4 acc = {0.f,0.f,0.f,0.f};
    const bf16x8* wf = FRbase + (size_t)nt*KT*64 + lane;
    #pragma unroll
    for (int kc = 0; kc < KT; ++kc) acc = MFMA(af[kc], wf[kc*64], acc);
    const int col = nt*16 + (lane & 15);
    if (col < H) {
      const int rbase = (lane >> 4)*4;
      #pragma unroll
      for (int r = 0; r < 4; ++r)
        dst[(size_t)(rbase + r)*ST + col] = (__bf16)fmaxf(acc[r], 0.f);
    }
  }
}

// K-concat single-tile (two 4-frag A arrays)
DEVFN void layerHcat1(const bf16x8 (&a0)[4], const bf16x8 (&a1)[4], const bf16x8* FRbase,
                      __bf16* dst, int nt, int lane)
{
  f32x4 acc = {0.f,0.f,0.f,0.f};
  const bf16x8* wf = FRbase + (size_t)nt*8*64 + lane;
  #pragma unroll
  for (int kc = 0; kc < 4; ++kc) acc = MFMA(a0[kc], wf[kc*64], acc);
  #pragma unroll
  for (int kc = 0; kc < 4; ++kc) acc = MFMA(a1[kc], wf[(4+kc)*64], acc);
  const int col = nt*16 + (lane & 15);
  if (col < H) {
    const int rbase = (lane >> 4)*4;
    #pragma unroll
    for (int r = 0; r < 4; ++r)
      dst[(size_t)(rbase + r)*ST + col] = (__bf16)fmaxf(acc[r], 0.f);
  }
}

template<int KT>
DEVFN f32x4 head4(const bf16x8 (&af)[KT], const bf16x8* FRbase, int lane)
{
  f32x4 acc = {0.f,0.f,0.f,0.f};
  #pragma unroll
  for (int kc = 0; kc < KT; ++kc) acc = MFMA(af[kc], FRbase[kc*64 + lane], acc);
  return acc;
}

// launch_bounds(256,3): budget 512/3 = 170 regs/thread -> 3 waves/SIMD = 12 waves/CU.
// History: (256,2) -> 256-reg alloc -> reg-cap 8 waves/CU (R2 measured 23% occ with grid
// allowing 16). (256,4) -> 128-reg budget with ~190-reg demand -> catastrophic spill (R1).
// Single-M tiles cap peak demand at ~135 (P5: 48 frag + 24 acc + ~36 weights + addr),
// which fits 170 with slack. If OccupancyPercent stays ~23 or WRITE_SIZE >> 10MB,
// this bet failed -- revert to R7.
__global__ __launch_bounds__(NTH, 3) void vrnn_kernel(Params P, const __bf16* FRW)
{
  // sPX and sB double-buffered by t-parity: no end-of-step barrier, P7(t) NLL overlaps
  // P1(t+1). ~28KB LDS -> LDS allows 5 blocks/CU; regs cap at 3.
  __shared__ alignas(16) __bf16 sPXb[2][HBUF];
  __shared__ alignas(16) __bf16 sPZ[HBUF];
  __shared__ alignas(16) __bf16 sA [HBUF];   // he -> hd1
  __shared__ alignas(16) __bf16 sBb[2][HBUF];// hp -> hd2
  __shared__ alignas(16) __bf16 sH0[HBUF];   // h double-buffer (no in-place GRU hazard, no pre-barrier)
  __shared__ alignas(16) __bf16 sH1[HBUF];
  __shared__ alignas(16) __bf16 sZ [ROWS*XST];
  __shared__ float sred[8];

  const bf16x8* FR = (const bf16x8*)FRW;
  const int tid  = threadIdx.x;
  const int lane = tid & 63;
  const int wv   = tid >> 6;       // 0..3
  const int gr0  = blockIdx.x * ROWS;

  // zero-init ALL LDS, then plant bias-activation 1.0 at the K-pad column.
  for (int i = tid; i < HBUF; i += NTH) {
    sPXb[0][i]=(__bf16)0.f; sPXb[1][i]=(__bf16)0.f; sPZ[i]=(__bf16)0.f; sA[i]=(__bf16)0.f;
    sBb[0][i]=(__bf16)0.f; sBb[1][i]=(__bf16)0.f; sH0[i]=(__bf16)0.f; sH1[i]=(__bf16)0.f;
  }
  for (int i = tid; i < ROWS*XST; i += NTH) sZ[i]=(__bf16)0.f;
  __syncthreads();
  if (tid < ROWS) {
    sPXb[0][tid*ST+100]=(__bf16)1.f; sPXb[1][tid*ST+100]=(__bf16)1.f;
    sPZ[tid*ST+100]=(__bf16)1.f; sA[tid*ST+100]=(__bf16)1.f;
    sBb[0][tid*ST+100]=(__bf16)1.f; sBb[1][tid*ST+100]=(__bf16)1.f;
    sH0[tid*ST+100]=(__bf16)1.f; sH1[tid*ST+100]=(__bf16)1.f;
    sZ[tid*XST+16]=(__bf16)1.f;
  }
  __syncthreads();

  float kl = 0.f, nll = 0.f;

  for (int t = 0; t < T; ++t) {
    __bf16* sHo = (t & 1) ? sH1 : sH0;   // h(t-1) (t=0 reads zeroed sH0)
    __bf16* sHn = (t & 1) ? sH0 : sH1;   // h(t)
    __bf16* sPX = sPXb[t & 1];
    __bf16* sB  = sBb [t & 1];

    // ---- P1: px = relu(x Wpx^T + b) (x A-frag from global, bias-one at k=28) ; hp -> sB
    {
      const int m = lane & 15, quad = lane >> 4;
      const float* xr = P.x + ((size_t)t*B + gr0 + m)*X + quad*8;
      float4 fa = *(const float4*)xr;
      float4 fb = make_float4(0.f,0.f,0.f,0.f);
      if (quad < 3) fb = *(const float4*)(xr + 4);
      bf16x8 ax;
      ax[0]=(__bf16)fa.x; ax[1]=(__bf16)fa.y; ax[2]=(__bf16)fa.z; ax[3]=(__bf16)fa.w;
      ax[4]=(__bf16)fb.x; ax[5]=(__bf16)fb.y; ax[6]=(__bf16)fb.z; ax[7]=(__bf16)fb.w;
      if (quad == 3) ax[4] = (__bf16)1.f;    // k=28 bias slot
      bf16x8 axA[1] = {ax};
      layerH<1,1>(axA, FR + (size_t)FB_PX*64, sPX, wv, 4, lane);
      bf16x8 ah[4]; load_afrags(ah, sHo, ST, lane);
      layerH<4,4>(ah, FR + (size_t)FB_HP*64, sB, (wv + 1) & 3, 4, lane);  // offset balances wave3's 1-tile px
    }
    __syncthreads();   // B1

    // ---- P2: he = relu([px|h] We1^T + b) -> sA
    {
      bf16x8 a0[4]; load_afrags(a0, sPX, ST, lane);
      bf16x8 a1[4]; load_afrags(a1, sHo, ST, lane);
      for (int nt = wv; nt < 7; nt += 4)
        layerHcat1(a0, a1, FR + (size_t)FB_HE*64, sA, nt, lane);
    }
    __syncthreads();   // B2

    // ---- P3 (no barrier): ALL waves compute all 4 Z-heads; z dup-written (identical values);
    //      KL split by acc-reg index (r == wv covers every row exactly once across waves)
    {
      bf16x8 a1[4]; load_afrags(a1, sA, ST, lane);
      bf16x8 a2[4]; load_afrags(a2, sB, ST, lane);
      f32x4 emu = head4(a1, FR + (size_t)FB_EMU*64,  lane);
      f32x4 esg = head4(a1, FR + (size_t)FB_ESIG*64, lane);
      f32x4 pmu = head4(a2, FR + (size_t)FB_PMU*64,  lane);
      f32x4 psg = head4(a2, FR + (size_t)FB_PSIG*64, lane);
      const int zi = lane & 15;
      const int rbase = (lane >> 4)*4;
      #pragma unroll
      for (int r = 0; r < 4; ++r) {
        float em = emu[r];
        float es = fsoftplus(esg[r]);
        float ev = P.eps[((size_t)t*B + gr0 + rbase + r)*Z + zi];
        sZ[(rbase + r)*XST + zi] = (__bf16)(em + __builtin_amdgcn_sqrtf(es)*ev);
        if (r == wv) {
          float ps = fsoftplus(psg[r]) + KEPS;
          float dm = em - pmu[r];
          float rps = frcp(ps);
          kl += 0.5f*(2.f*__logf(ps*frcp(es)) + (es*es + dm*dm)*(rps*rps) - 1.f);
        }
      }
    }
    // no barrier: each wave wrote all of sZ itself and reads only its own writes below

    // ---- P4: pz = relu(z Wpz^T + b) -> sPZ  (bias-one at z col 16)
    {
      bf16x8 az[1];
      az[0] = *(const bf16x8*)(sZ + (size_t)(lane & 15)*XST + (lane >> 4)*8);
      layerH<1,1>(az, FR + (size_t)FB_PZ*64, sPZ, wv, 4, lane);
    }
    __syncthreads();   // B4

    // ---- P5: hd1 -> sA ; fused GRU sHo -> sHn (double-buffered h: no pre-barrier needed)
    {
      bf16x8 apz[4]; load_afrags(apz, sPZ, ST, lane);
      bf16x8 ah [4]; load_afrags(ah,  sHo, ST, lane);

      // hd1 split: waves 0-2 take odd tiles {1,3,5}; wave 3 takes even tiles {0,2,4,6}
      // (wave 3 has only 1 GRU tile below)
      if (wv == 3) {
        for (int nt = 0; nt < 7; nt += 2)
          layerHcat1(apz, ah, FR + (size_t)FB_HD1*64, sA, nt, lane);
      } else {
        layerHcat1(apz, ah, FR + (size_t)FB_HD1*64, sA, 2*wv + 1, lane);
      }

      bf16x8 apx[4]; load_afrags(apx, sPX, ST, lane);

      for (int c = wv; c < 7; c += 4) {
        f32x4 gr={0.f,0.f,0.f,0.f}, gu={0.f,0.f,0.f,0.f}, gn={0.f,0.f,0.f,0.f};
        const bf16x8* wr = FR + (size_t)(FB_GIR + c*8)*64 + lane;
        const bf16x8* wu = FR + (size_t)(FB_GIU + c*8)*64 + lane;
        const bf16x8* wn = FR + (size_t)(FB_GIN + c*8)*64 + lane;
        #pragma unroll
        for (int kc = 0; kc < 4; ++kc) {        // gi part 1: pz (bih folded here)
          bf16x8 a = apz[kc];
          gr = MFMA(a, wr[kc*64], gr); gu = MFMA(a, wu[kc*64], gu); gn = MFMA(a, wn[kc*64], gn);
        }
        #pragma unroll
        for (int kc = 0; kc < 4; ++kc) {        // gi part 2: px
          bf16x8 a = apx[kc];
          gr = MFMA(a, wr[(4+kc)*64], gr); gu = MFMA(a, wu[(4+kc)*64], gu); gn = MFMA(a, wn[(4+kc)*64], gn);
        }
        f32x4 hr={0.f,0.f,0.f,0.f}, hu={0.f,0.f,0.f,0.f}, hn={0.f,0.f,0.f,0.f};
        const bf16x8* vr = FR + (size_t)(FB_GHR + c*4)*64 + lane;
        const bf16x8* vu = FR + (size_t)(FB_GHU + c*4)*64 + lane;
        const bf16x8* vn = FR + (size_t)(FB_GHN + c*4)*64 + lane;
        #pragma unroll
        for (int kc = 0; kc < 4; ++kc) {        // gh: h (bhh folded here)
          bf16x8 a = ah[kc];
          hr = MFMA(a, vr[kc*64], hr); hu = MFMA(a, vu[kc*64], hu); hn = MFMA(a, vn[kc*64], hn);
        }
        const int n = c*16 + (lane & 15);
        if (n < H) {
          const int rbase = (lane >> 4)*4;
          #pragma unroll
          for (int r = 0; r < 4; ++r) {
            float rr = fsigmoid(gr[r] + hr[r]);
            float uu = fsigmoid(gu[r] + hu[r]);
            float nn = ftanh(gn[r] + rr*hn[r]);
            const size_t off = (size_t)(rbase + r)*ST + n;
            float ho = (float)sHo[off];
            sHn[off] = (__bf16)((1.f-uu)*nn + uu*ho);
          }
        }
      }
    }
    __syncthreads();   // B5

    // ---- P6: hd2 = relu(hd1 Wd2^T + b) : sA -> sB
    {
      bf16x8 af[4]; load_afrags(af, sA, ST, lane);
      layerH<4,4>(af, FR + (size_t)FB_HD2*64, sB, wv, 4, lane);
    }
    __syncthreads();   // B6

    // ---- P7: logits v = hd2 Wd3^T + b ; NLL via log-sigmoid identity
    //      4-way split: tile = wv&1, row-half = wv>>1 (head4 computed redundantly x2 per tile)
    //      NO trailing barrier: sPX/sB are t-parity double-buffered; any wave entering
    //      P1(t+1) already passed B6(t) => sHn complete and opposite-parity writes only.
    {
      bf16x8 af[4]; load_afrags(af, sB, ST, lane);
      const int pt = wv & 1;
      const int rh = (wv >> 1) * 2;
      f32x4 acc = head4(af, FR + (size_t)(FB_PRB + pt*4)*64, lane);
      const int n = pt*16 + (lane & 15);
      if (n < X) {
        const int rbase = (lane >> 4)*4;
        #pragma unroll
        for (int rr = 0; rr < 2; ++rr) {
          const int r = rh + rr;
          float v  = acc[r];
          float xv = P.x[((size_t)t*B + gr0 + rbase + r)*X + n];
          nll += fmaxf(-v, 0.f) + __logf(1.f + __expf(-fabsf(v))) + (1.f - xv)*v;
        }
      }
    }
  } // t

  __syncthreads();   // seal last step before reduction

  // ---- reduce kl/nll: wave shuffle -> LDS -> one atomicAdd per block
  for (int off = 32; off > 0; off >>= 1) {
    kl  += __shfl_down(kl,  off);
    nll += __shfl_down(nll, off);
  }
  if (lane == 0) { sred[wv] = kl; sred[4 + wv] = nll; }
  __syncthreads();
  if (tid == 0) {
    atomicAdd(&P.out[0], (sred[0] + sred[1] + sred[2] + sred[3]) * (1.f/(float)B));
    atomicAdd(&P.out[1], (sred[4] + sred[5] + sred[6] + sred[7]) * (1.f/(float)B));
  }
}

} // namespace

extern "C" void kernel_launch(void* const* d_in, const int* in_sizes, int n_in,
                              void* d_out, int out_size, void* d_ws, size_t ws_size,
                              hipStream_t stream)
{
  Params p;
  const float* const* f = (const float* const*)d_in;
  p.x=f[0];    p.eps=f[1];
  p.Wpx=f[2];  p.bpx=f[3];   p.Wpz=f[4];   p.bpz=f[5];
  p.Wp1=f[6];  p.bp1=f[7];   p.Wp_mu=f[8]; p.bp_mu=f[9];
  p.Wp_sig=f[10]; p.bp_sig=f[11];
  p.We1=f[12]; p.be1=f[13];  p.We_mu=f[14]; p.be_mu=f[15];
  p.We_sig=f[16]; p.be_sig=f[17];
  p.Wd1=f[18]; p.bd1=f[19];  p.Wd2=f[20];  p.bd2=f[21];
  p.Wd3=f[22]; p.bd3=f[23];
  p.Wih=f[24]; p.Whh=f[25];  p.bih=f[26];  p.bhh=f[27];
  p.out = (float*)d_out;

  hipMemsetAsync(d_out, 0, 2*sizeof(float), stream);
  prep_kernel<<<dim3(NFRAG), dim3(64), 0, stream>>>(p, (__bf16*)d_ws);
  vrnn_kernel<<<dim3(B/ROWS), dim3(NTH), 0, stream>>>(p, (const __bf16*)d_ws);
}

// Round 9
// 632.939 us; speedup vs baseline: 2.5582x; 2.5582x over previous
//
#include <hip/hip_runtime.h>
#include <math.h>

#define DEVFN __device__ __forceinline__

namespace {

typedef __bf16 bf16x8 __attribute__((ext_vector_type(8)));
typedef float  f32x4  __attribute__((ext_vector_type(4)));

constexpr int T = 28, B = 16384, X = 28, H = 100, Z = 16;
constexpr int ROWS = 32;           // TWO 16-row M-tiles per block: each weight-fragment load feeds 2 MFMAs
constexpr int NTH  = 256;          // 4 waves; grid 512 -> 2 blocks/CU x 4 waves = 8 waves/CU
constexpr int ST   = 104;          // bf16 LDS stride; col 100 = bias-one, 101+ zero
constexpr int HBUF = ROWS*ST + 24; // tail pad: row-31 kc=3 frag overrun stays in-buffer (zeroed)
constexpr int XST  = 40;           // stride for Z rows
constexpr float KEPS = 1e-10f;

// ---- weight-fragment table (1 frag = 16x32 B-tile = 64 lanes x 16B = 1024B) ----
constexpr int FB_PX   = 0;    // 7   KT=1
constexpr int FB_HE   = 7;    // 56  KT=8 (concat px|h)
constexpr int FB_EMU  = 63;   // 4   KT=4
constexpr int FB_ESIG = 67;   // 4
constexpr int FB_HP   = 71;   // 28  KT=4
constexpr int FB_PMU  = 99;   // 4
constexpr int FB_PSIG = 103;  // 4
constexpr int FB_PZ   = 107;  // 7   KT=1
constexpr int FB_HD1  = 114;  // 56  KT=8 (concat pz|h)
constexpr int FB_HD2  = 170;  // 28  KT=4
constexpr int FB_PRB  = 198;  // 8   KT=4 (Nt=2)
constexpr int FB_GIR  = 206;  // 56  KT=8 (concat pz|px)
constexpr int FB_GIU  = 262;  // 56
constexpr int FB_GIN  = 318;  // 56
constexpr int FB_GHR  = 374;  // 28  KT=4
constexpr int FB_GHU  = 402;  // 28
constexpr int FB_GHN  = 430;  // 28
constexpr int NFRAG   = 458;  // 469 KB in d_ws

struct Params {
  const float *x,*eps,*Wpx,*bpx,*Wpz,*bpz,*Wp1,*bp1,*Wp_mu,*bp_mu,*Wp_sig,*bp_sig,
              *We1,*be1,*We_mu,*be_mu,*We_sig,*be_sig,*Wd1,*bd1,*Wd2,*bd2,*Wd3,*bd3,
              *Wih,*Whh,*bih,*bhh;
  float *out;
};

DEVFN float frcp(float x){ return __builtin_amdgcn_rcpf(x); }
DEVFN float fsigmoid(float v){ return frcp(1.f + __expf(-v)); }
DEVFN float ftanh(float v){
  float t = __expf(-2.f*fabsf(v));           // (0,1], no overflow
  float r = (1.f - t) * frcp(1.f + t);
  return copysignf(r, v);
}
DEVFN float fsoftplus(float v){
  float sp = (v > 15.f) ? v : __logf(1.f + __expf(v));
  return fmaxf(sp, 1e-6f);                   // log/rcp safety in KL tail
}

DEVFN f32x4 MFMA(bf16x8 a, bf16x8 b, f32x4 c){
  return __builtin_amdgcn_mfma_f32_16x16x32_bf16(a, b, c, 0, 0, 0);
}

// ---------------- weight prep: fp32 -> bf16 B-fragments, biases folded into K-pad slot ----------------
__global__ void prep_kernel(Params P, __bf16* FRW)
{
  const int f = blockIdx.x, l = threadIdx.x;
  const int bases[18] = {FB_PX,FB_HE,FB_EMU,FB_ESIG,FB_HP,FB_PMU,FB_PSIG,FB_PZ,FB_HD1,
                         FB_HD2,FB_PRB,FB_GIR,FB_GIU,FB_GIN,FB_GHR,FB_GHU,FB_GHN,NFRAG};
  int li = 0;
  while (f >= bases[li+1]) ++li;

  const float* W; const float* Bv; int KT, N, roff, wstr, vK, mode;
  switch (li) {
    case 0:  W=P.Wpx;    Bv=P.bpx;    KT=1; N=100; roff=0;   wstr=28;  vK=28;  mode=0; break;
    case 1:  W=P.We1;    Bv=P.be1;    KT=8; N=100; roff=0;   wstr=200; vK=100; mode=1; break;
    case 2:  W=P.We_mu;  Bv=P.be_mu;  KT=4; N=16;  roff=0;   wstr=100; vK=100; mode=0; break;
    case 3:  W=P.We_sig; Bv=P.be_sig; KT=4; N=16;  roff=0;   wstr=100; vK=100; mode=0; break;
    case 4:  W=P.Wp1;    Bv=P.bp1;    KT=4; N=100; roff=0;   wstr=100; vK=100; mode=0; break;
    case 5:  W=P.Wp_mu;  Bv=P.bp_mu;  KT=4; N=16;  roff=0;   wstr=100; vK=100; mode=0; break;
    case 6:  W=P.Wp_sig; Bv=P.bp_sig; KT=4; N=16;  roff=0;   wstr=100; vK=100; mode=0; break;
    case 7:  W=P.Wpz;    Bv=P.bpz;    KT=1; N=100; roff=0;   wstr=16;  vK=16;  mode=0; break;
    case 8:  W=P.Wd1;    Bv=P.bd1;    KT=8; N=100; roff=0;   wstr=200; vK=100; mode=1; break;
    case 9:  W=P.Wd2;    Bv=P.bd2;    KT=4; N=100; roff=0;   wstr=100; vK=100; mode=0; break;
    case 10: W=P.Wd3;    Bv=P.bd3;    KT=4; N=28;  roff=0;   wstr=100; vK=100; mode=0; break;
    case 11: W=P.Wih;    Bv=P.bih;    KT=8; N=100; roff=0;   wstr=200; vK=100; mode=1; break;
    case 12: W=P.Wih;    Bv=P.bih;    KT=8; N=100; roff=100; wstr=200; vK=100; mode=1; break;
    case 13: W=P.Wih;    Bv=P.bih;    KT=8; N=100; roff=200; wstr=200; vK=100; mode=1; break;
    case 14: W=P.Whh;    Bv=P.bhh;    KT=4; N=100; roff=0;   wstr=100; vK=100; mode=0; break;
    case 15: W=P.Whh;    Bv=P.bhh;    KT=4; N=100; roff=100; wstr=100; vK=100; mode=0; break;
    default: W=P.Whh;    Bv=P.bhh;    KT=4; N=100; roff=200; wstr=100; vK=100; mode=0; break;
  }
  const int idx = f - bases[li];
  const int nt = idx / KT, kc = idx % KT;
  const int n  = nt*16 + (l & 15);

  bf16x8 v;
  #pragma unroll
  for (int j = 0; j < 8; ++j) {
    int kk  = (mode ? (kc & 3) : kc)*32 + ((l >> 4)*8) + j;
    float w = 0.f;
    if (n < N) {
      if (mode == 0) {
        if (kk < vK)       w = W[(size_t)(roff + n)*wstr + kk];
        else if (kk == vK) w = Bv[roff + n];                      // bias in K-pad slot
      } else {
        int col = (kc < 4 ? 0 : 100) + kk;
        if (kk < 100)                    w = W[(size_t)(roff + n)*wstr + col];
        else if (kc < 4 && kk == 100)    w = Bv[roff + n];        // bias in segment-0 pad slot
      }
    }
    v[j] = (__bf16)w;
  }
  *((bf16x8*)FRW + (size_t)f*64 + l) = v;
}

// ---------------- main kernel helpers (two M-halves share every weight-fragment load) ----------------
template<int NC>
DEVFN void load_afrags2(bf16x8 (&af)[2][NC], const __bf16* A, int stride, int lane)
{
  #pragma unroll
  for (int mh = 0; mh < 2; ++mh) {
    const __bf16* p = A + (size_t)((lane & 15) + mh*16)*stride + ((lane >> 4)*8);
    #pragma unroll
    for (int kc = 0; kc < NC; ++kc) af[mh][kc] = *(const bf16x8*)(p + kc*32);
  }
}

// volatile single-fragment LDS read: cannot be hoisted/CSE'd -> transient 4-VGPR lifetime.
// Used in the GRU loop to cap register pressure (the R3..R6 29MB scratch spill).
DEVFN bf16x8 vload_frag(const __bf16* A, int stride, int mh, int kc, int lane)
{
  const __bf16* p = A + (size_t)((lane & 15) + mh*16)*stride + ((lane >> 4)*8) + kc*32;
  return *(const volatile bf16x8*)p;
}

// H-output layer, both M-halves: one weight load -> two MFMAs
template<int KT>
DEVFN void layerH2(const bf16x8 (&af)[2][KT], const bf16x8* FRbase, __bf16* dst, int sw, int step, int lane)
{
  for (int nt = sw; nt < 7; nt += step) {
    f32x4 ac0 = {0.f,0.f,0.f,0.f}, ac1 = {0.f,0.f,0.f,0.f};
    const bf16x8* wf = FRbase + (size_t)nt*KT*64 + lane;
    #pragma unroll
    for (int kc = 0; kc < KT; ++kc) {
      bf16x8 w = wf[kc*64];
      ac0 = MFMA(af[0][kc], w, ac0);
      ac1 = MFMA(af[1][kc], w, ac1);
    }
    const int col = nt*16 + (lane & 15);
    if (col < H) {
      const int rbase = (lane >> 4)*4;
      #pragma unroll
      for (int r = 0; r < 4; ++r) {
        dst[(size_t)(rbase + r)*ST + col]      = (__bf16)fmaxf(ac0[r], 0.f);
        dst[(size_t)(16 + rbase + r)*ST + col] = (__bf16)fmaxf(ac1[r], 0.f);
      }
    }
  }
}

// K-concat single-tile, both M-halves
DEVFN void layerHcat2_1(const bf16x8 (&b0)[2][4], const bf16x8 (&b1)[2][4], const bf16x8* FRbase,
                        __bf16* dst, int nt, int lane)
{
  f32x4 ac0 = {0.f,0.f,0.f,0.f}, ac1 = {0.f,0.f,0.f,0.f};
  const bf16x8* wf = FRbase + (size_t)nt*8*64 + lane;
  #pragma unroll
  for (int kc = 0; kc < 4; ++kc) {
    bf16x8 w = wf[kc*64];
    ac0 = MFMA(b0[0][kc], w, ac0);
    ac1 = MFMA(b0[1][kc], w, ac1);
  }
  #pragma unroll
  for (int kc = 0; kc < 4; ++kc) {
    bf16x8 w = wf[(4+kc)*64];
    ac0 = MFMA(b1[0][kc], w, ac0);
    ac1 = MFMA(b1[1][kc], w, ac1);
  }
  const int col = nt*16 + (lane & 15);
  if (col < H) {
    const int rbase = (lane >> 4)*4;
    #pragma unroll
    for (int r = 0; r < 4; ++r) {
      dst[(size_t)(rbase + r)*ST + col]      = (__bf16)fmaxf(ac0[r], 0.f);
      dst[(size_t)(16 + rbase + r)*ST + col] = (__bf16)fmaxf(ac1[r], 0.f);
    }
  }
}

template<int KT>
DEVFN void head4x2(const bf16x8 (&af)[2][KT], const bf16x8* FRbase, int lane, f32x4& o0, f32x4& o1)
{
  f32x4 ac0 = {0.f,0.f,0.f,0.f}, ac1 = {0.f,0.f,0.f,0.f};
  #pragma unroll
  for (int kc = 0; kc < KT; ++kc) {
    bf16x8 w = FRbase[kc*64 + lane];
    ac0 = MFMA(af[0][kc], w, ac0);
    ac1 = MFMA(af[1][kc], w, ac1);
  }
  o0 = ac0; o1 = ac1;
}

// single-M head (P7 quadrant)
template<int KT>
DEVFN f32x4 head4(const bf16x8 (&af)[KT], const bf16x8* FRbase, int lane)
{
  f32x4 acc = {0.f,0.f,0.f,0.f};
  #pragma unroll
  for (int kc = 0; kc < KT; ++kc) acc = MFMA(af[kc], FRbase[kc*64 + lane], acc);
  return acc;
}

// launch_bounds MUST stay (NTH,2): the allocator always squeezes arch regs to the
// min-waves target: (256,4)->64 arch [R1 spill], (256,3)->84 arch [R8 spill],
// (256,2)->128 arch [no spill]. 8 waves/CU is where grid cap and reg cap meet.
// NO accumulators carried across barriers (R4: +48 live VGPR across B4 => 313MB spill).
// P5 liveness capped via scoped hd1 + per-kc volatile A-frag reloads (R7: 29MB->7MB spill).
// R9: all work-split indices go through readfirstlane so weight addressing is provably
// wave-uniform -> SGPR base + saddr loads instead of per-load 64-bit VALU address math
// (~130 weight loads/wave/step x ~3 VALU each was the suspected VALUBusy bulk).
__global__ __launch_bounds__(NTH, 2) void vrnn_kernel(Params P, const __bf16* FRW)
{
  // sPX and sB double-buffered by t-parity: removes the end-of-step barrier, so
  // P7(t) (VALU-heavy NLL) overlaps P1(t+1) (load-heavy). ~56KB LDS, 2 blocks/CU.
  __shared__ alignas(16) __bf16 sPXb[2][HBUF];
  __shared__ alignas(16) __bf16 sPZ[HBUF];
  __shared__ alignas(16) __bf16 sA [HBUF];   // he -> hd1
  __shared__ alignas(16) __bf16 sBb[2][HBUF];// hp -> hd2
  __shared__ alignas(16) __bf16 sH0[HBUF];   // h double-buffer
  __shared__ alignas(16) __bf16 sH1[HBUF];
  __shared__ alignas(16) __bf16 sZ [ROWS*XST];
  __shared__ float sred[8];

  const bf16x8* FR = (const bf16x8*)FRW;
  const int tid  = threadIdx.x;
  const int lane = tid & 63;
  // wave id, forced into an SGPR: it IS wave-uniform, but the compiler cannot prove
  // tid>>6 uniform. Scalarizing it makes every weight-fragment offset and loop bound
  // scalar -> SALU addressing + saddr global loads.
  const int uwv  = __builtin_amdgcn_readfirstlane(tid >> 6);   // 0..3
  const int gr0  = blockIdx.x * ROWS;

  // zero-init ALL LDS, then plant bias-activation 1.0 at the K-pad column.
  for (int i = tid; i < HBUF; i += NTH) {
    sPXb[0][i]=(__bf16)0.f; sPXb[1][i]=(__bf16)0.f; sPZ[i]=(__bf16)0.f; sA[i]=(__bf16)0.f;
    sBb[0][i]=(__bf16)0.f; sBb[1][i]=(__bf16)0.f; sH0[i]=(__bf16)0.f; sH1[i]=(__bf16)0.f;
  }
  for (int i = tid; i < ROWS*XST; i += NTH) sZ[i]=(__bf16)0.f;
  __syncthreads();
  if (tid < ROWS) {
    sPXb[0][tid*ST+100]=(__bf16)1.f; sPXb[1][tid*ST+100]=(__bf16)1.f;
    sPZ[tid*ST+100]=(__bf16)1.f; sA[tid*ST+100]=(__bf16)1.f;
    sBb[0][tid*ST+100]=(__bf16)1.f; sBb[1][tid*ST+100]=(__bf16)1.f;
    sH0[tid*ST+100]=(__bf16)1.f; sH1[tid*ST+100]=(__bf16)1.f;
    sZ[tid*XST+16]=(__bf16)1.f;
  }
  __syncthreads();

  float kl = 0.f, nll = 0.f;

  for (int t = 0; t < T; ++t) {
    __bf16* sHo = (t & 1) ? sH1 : sH0;   // h from previous step (t=0 reads zeroed sH0)
    __bf16* sHn = (t & 1) ? sH0 : sH1;   // h for next step
    __bf16* sPX = sPXb[t & 1];
    __bf16* sB  = sBb [t & 1];

    // ---- P1: px = relu(x Wpx^T + b) (x A-frags from global, bias-one at k=28) ; hp -> sB
    {
      bf16x8 ax[2][1];
      #pragma unroll
      for (int mh = 0; mh < 2; ++mh) {
        const float* xr = P.x + ((size_t)t*B + gr0 + mh*16 + (lane & 15))*X + (lane >> 4)*8;
        float4 fa = *(const float4*)xr;
        float4 fb = make_float4(0.f,0.f,0.f,0.f);
        if ((lane >> 4) < 3) fb = *(const float4*)(xr + 4);
        bf16x8 a;
        a[0]=(__bf16)fa.x; a[1]=(__bf16)fa.y; a[2]=(__bf16)fa.z; a[3]=(__bf16)fa.w;
        a[4]=(__bf16)fb.x; a[5]=(__bf16)fb.y; a[6]=(__bf16)fb.z; a[7]=(__bf16)fb.w;
        if ((lane >> 4) == 3) a[4] = (__bf16)1.f;    // k=28 bias slot
        ax[mh][0] = a;
      }
      layerH2<1>(ax, FR + (size_t)FB_PX*64, sPX, uwv, 4, lane);
      bf16x8 ah[2][4]; load_afrags2(ah, sHo, ST, lane);
      layerH2<4>(ah, FR + (size_t)FB_HP*64, sB, (uwv + 1) & 3, 4, lane); // offset balances wave3's 1-tile px
    }
    __syncthreads();   // B1

    // ---- P2: he = relu([px|h] We1^T + b) -> sA
    {
      bf16x8 a0[2][4]; load_afrags2(a0, sPX, ST, lane);
      bf16x8 a1[2][4]; load_afrags2(a1, sHo, ST, lane);
      for (int nt = uwv; nt < 7; nt += 4)
        layerHcat2_1(a0, a1, FR + (size_t)FB_HE*64, sA, nt, lane);
    }
    __syncthreads();   // B2

    // ---- P3 (no barrier): ALL waves compute all 4 Z-heads for both M-halves; z dup-written;
    //      KL split by acc-reg index (r == uwv covers every row exactly once across waves)
    {
      bf16x8 a1[2][4]; load_afrags2(a1, sA, ST, lane);
      bf16x8 a2[2][4]; load_afrags2(a2, sB, ST, lane);
      f32x4 emu[2], esg[2], pmu[2], psg[2];
      head4x2(a1, FR + (size_t)FB_EMU*64,  lane, emu[0], emu[1]);
      head4x2(a1, FR + (size_t)FB_ESIG*64, lane, esg[0], esg[1]);
      head4x2(a2, FR + (size_t)FB_PMU*64,  lane, pmu[0], pmu[1]);
      head4x2(a2, FR + (size_t)FB_PSIG*64, lane, psg[0], psg[1]);
      const int zi = lane & 15;
      const int rbase = (lane >> 4)*4;
      #pragma unroll
      for (int mh = 0; mh < 2; ++mh) {
        #pragma unroll
        for (int r = 0; r < 4; ++r) {
          float em = emu[mh][r];
          float es = fsoftplus(esg[mh][r]);
          float ev = P.eps[((size_t)t*B + gr0 + mh*16 + rbase + r)*Z + zi];
          sZ[(mh*16 + rbase + r)*XST + zi] = (__bf16)(em + __builtin_amdgcn_sqrtf(es)*ev);
          if (r == uwv) {
            float ps = fsoftplus(psg[mh][r]) + KEPS;
            float dm = em - pmu[mh][r];
            float rps = frcp(ps);
            kl += 0.5f*(2.f*__logf(ps*frcp(es)) + (es*es + dm*dm)*(rps*rps) - 1.f);
          }
        }
      }
    }
    // no barrier: each wave wrote all of sZ itself and reads only its own writes below

    // ---- P4: pz = relu(z Wpz^T + b) -> sPZ  (bias-one at z col 16)
    {
      bf16x8 az[2][1];
      #pragma unroll
      for (int mh = 0; mh < 2; ++mh)
        az[mh][0] = *(const bf16x8*)(sZ + (size_t)((lane & 15) + mh*16)*XST + (lane >> 4)*8);
      layerH2<1>(az, FR + (size_t)FB_PZ*64, sPZ, uwv, 4, lane);
    }
    __syncthreads();   // B4

    // ---- P5: hd1 -> sA ; fused GRU sHo -> sHn.  LIVENESS-CAPPED (R7):
    //      hd1's A-frags are scoped; the GRU loop reloads A-frags per-kc via volatile
    //      LDS reads so at most one gate-stage's accumulators + an 8-reg transient are
    //      live at once (replaces the 29MB/dispatch compiler spill of R3..R6).
    {
      {  // hd1 sub-phase: frags die here
        bf16x8 apz[2][4]; load_afrags2(apz, sPZ, ST, lane);
        bf16x8 ah [2][4]; load_afrags2(ah,  sHo, ST, lane);
        if (uwv == 3) {
          for (int nt = 0; nt < 7; nt += 2)
            layerHcat2_1(apz, ah, FR + (size_t)FB_HD1*64, sA, nt, lane);
        } else {
          layerHcat2_1(apz, ah, FR + (size_t)FB_HD1*64, sA, 2*uwv + 1, lane);
        }
      }

      #pragma unroll 1
      for (int c = uwv; c < 7; c += 4) {
        const f32x4 z4 = {0.f,0.f,0.f,0.f};
        f32x4 gr[2]={z4,z4}, gu[2]={z4,z4}, gn[2]={z4,z4};
        const bf16x8* wr = FR + (size_t)(FB_GIR + c*8)*64 + lane;
        const bf16x8* wu = FR + (size_t)(FB_GIU + c*8)*64 + lane;
        const bf16x8* wn = FR + (size_t)(FB_GIN + c*8)*64 + lane;
        #pragma unroll
        for (int kc = 0; kc < 4; ++kc) {        // gi part 1: pz (bih folded here)
          bf16x8 a0 = vload_frag(sPZ, ST, 0, kc, lane);
          bf16x8 a1 = vload_frag(sPZ, ST, 1, kc, lane);
          bf16x8 wR = wr[kc*64], wU = wu[kc*64], wN = wn[kc*64];
          gr[0] = MFMA(a0, wR, gr[0]); gu[0] = MFMA(a0, wU, gu[0]); gn[0] = MFMA(a0, wN, gn[0]);
          gr[1] = MFMA(a1, wR, gr[1]); gu[1] = MFMA(a1, wU, gu[1]); gn[1] = MFMA(a1, wN, gn[1]);
        }
        #pragma unroll
        for (int kc = 0; kc < 4; ++kc) {        // gi part 2: px
          bf16x8 a0 = vload_frag(sPX, ST, 0, kc, lane);
          bf16x8 a1 = vload_frag(sPX, ST, 1, kc, lane);
          bf16x8 wR = wr[(4+kc)*64], wU = wu[(4+kc)*64], wN = wn[(4+kc)*64];
          gr[0] = MFMA(a0, wR, gr[0]); gu[0] = MFMA(a0, wU, gu[0]); gn[0] = MFMA(a0, wN, gn[0]);
          gr[1] = MFMA(a1, wR, gr[1]); gu[1] = MFMA(a1, wU, gu[1]); gn[1] = MFMA(a1, wN, gn[1]);
        }
        f32x4 hr[2]={z4,z4}, hu[2]={z4,z4}, hn[2]={z4,z4};
        const bf16x8* vr = FR + (size_t)(FB_GHR + c*4)*64 + lane;
        const bf16x8* vu = FR + (size_t)(FB_GHU + c*4)*64 + lane;
        const bf16x8* vn = FR + (size_t)(FB_GHN + c*4)*64 + lane;
        #pragma unroll
        for (int kc = 0; kc < 4; ++kc) {        // gh: h (bhh folded here)
          bf16x8 a0 = vload_frag(sHo, ST, 0, kc, lane);
          bf16x8 a1 = vload_frag(sHo, ST, 1, kc, lane);
          bf16x8 wR = vr[kc*64], wU = vu[kc*64], wN = vn[kc*64];
          hr[0] = MFMA(a0, wR, hr[0]); hu[0] = MFMA(a0, wU, hu[0]); hn[0] = MFMA(a0, wN, hn[0]);
          hr[1] = MFMA(a1, wR, hr[1]); hu[1] = MFMA(a1, wU, hu[1]); hn[1] = MFMA(a1, wN, hn[1]);
        }
        const int n = c*16 + (lane & 15);
        if (n < H) {
          const int rbase = (lane >> 4)*4;
          #pragma unroll
          for (int mh = 0; mh < 2; ++mh) {
            #pragma unroll
            for (int r = 0; r < 4; ++r) {
              float rr = fsigmoid(gr[mh][r] + hr[mh][r]);
              float uu = fsigmoid(gu[mh][r] + hu[mh][r]);
              float nn = ftanh(gn[mh][r] + rr*hn[mh][r]);
              const size_t off = (size_t)(mh*16 + rbase + r)*ST + n;
              float ho = (float)sHo[off];
              sHn[off] = (__bf16)((1.f-uu)*nn + uu*ho);
            }
          }
        }
      }
    }
    __syncthreads();   // B5

    // ---- P6: hd2 = relu(hd1 Wd2^T + b) : sA -> sB
    {
      bf16x8 af[2][4]; load_afrags2(af, sA, ST, lane);
      layerH2<4>(af, FR + (size_t)FB_HD2*64, sB, uwv, 4, lane);
    }
    __syncthreads();   // B6

    // ---- P7: logits v = hd2 Wd3^T + b ; NLL via log-sigmoid identity
    //      quadrant split: N-tile = uwv&1, M-half = uwv>>1 (no redundancy)
    //      NO trailing barrier: sPX/sB are t-parity double-buffered; any wave entering
    //      P1(t+1) already passed B6(t) => sHn complete and opposite-parity writes only.
    {
      const int pt = uwv & 1;
      const int mh = uwv >> 1;
      bf16x8 af[4];
      const __bf16* p = sB + (size_t)((lane & 15) + mh*16)*ST + ((lane >> 4)*8);
      #pragma unroll
      for (int kc = 0; kc < 4; ++kc) af[kc] = *(const bf16x8*)(p + kc*32);
      f32x4 acc = head4(af, FR + (size_t)(FB_PRB + pt*4)*64, lane);
      const int n = pt*16 + (lane & 15);
      if (n < X) {
        const int rbase = (lane >> 4)*4;
        #pragma unroll
        for (int r = 0; r < 4; ++r) {
          float v  = acc[r];
          float xv = P.x[((size_t)t*B + gr0 + mh*16 + rbase + r)*X + n];
          nll += fmaxf(-v, 0.f) + __logf(1.f + __expf(-fabsf(v))) + (1.f - xv)*v;
        }
      }
    }
  } // t

  __syncthreads();   // seal last step before reduction

  // ---- reduce kl/nll: wave shuffle -> LDS -> one atomicAdd per block
  for (int off = 32; off > 0; off >>= 1) {
    kl  += __shfl_down(kl,  off);
    nll += __shfl_down(nll, off);
  }
  if (lane == 0) { sred[uwv] = kl; sred[4 + uwv] = nll; }
  __syncthreads();
  if (tid == 0) {
    atomicAdd(&P.out[0], (sred[0] + sred[1] + sred[2] + sred[3]) * (1.f/(float)B));
    atomicAdd(&P.out[1], (sred[4] + sred[5] + sred[6] + sred[7]) * (1.f/(float)B));
  }
}

} // namespace

extern "C" void kernel_launch(void* const* d_in, const int* in_sizes, int n_in,
                              void* d_out, int out_size, void* d_ws, size_t ws_size,
                              hipStream_t stream)
{
  Params p;
  const float* const* f = (const float* const*)d_in;
  p.x=f[0];    p.eps=f[1];
  p.Wpx=f[2];  p.bpx=f[3];   p.Wpz=f[4];   p.bpz=f[5];
  p.Wp1=f[6];  p.bp1=f[7];   p.Wp_mu=f[8]; p.bp_mu=f[9];
  p.Wp_sig=f[10]; p.bp_sig=f[11];
  p.We1=f[12]; p.be1=f[13];  p.We_mu=f[14]; p.be_mu=f[15];
  p.We_sig=f[16]; p.be_sig=f[17];
  p.Wd1=f[18]; p.bd1=f[19];  p.Wd2=f[20];  p.bd2=f[21];
  p.Wd3=f[22]; p.bd3=f[23];
  p.Wih=f[24]; p.Whh=f[25];  p.bih=f[26];  p.bhh=f[27];
  p.out = (float*)d_out;

  hipMemsetAsync(d_out, 0, 2*sizeof(float), stream);
  prep_kernel<<<dim3(NFRAG), dim3(64), 0, stream>>>(p, (__bf16*)d_ws);
  vrnn_kernel<<<dim3(B/ROWS), dim3(NTH), 0, stream>>>(p, (const __bf16*)d_ws);
}

// Round 10
// 603.682 us; speedup vs baseline: 2.6821x; 1.0485x over previous
//
#include <hip/hip_runtime.h>
#include <math.h>

#define DEVFN __device__ __forceinline__

namespace {

typedef __bf16 bf16x8 __attribute__((ext_vector_type(8)));
typedef float  f32x4  __attribute__((ext_vector_type(4)));

constexpr int T = 28, B = 16384, X = 28, H = 100, Z = 16;
constexpr int ROWS = 32;           // TWO 16-row M-tiles per block: each weight-fragment load feeds 2 MFMAs
constexpr int NTH  = 256;          // 4 waves; grid 512 -> 2 blocks/CU x 4 waves = 8 waves/CU
constexpr int ST   = 104;          // bf16 LDS stride; col 100 = bias-one, 101+ zero
constexpr int HBUF = ROWS*ST + 24; // tail pad: row-31 kc=3 frag overrun stays in-buffer (zeroed)
constexpr int XST  = 40;           // stride for Z rows
constexpr int HEST = 17;           // f32 stride for head-exchange rows (17 odd-ish: breaks 4-row bank alias)
constexpr float KEPS = 1e-10f;

// ---- weight-fragment table (1 frag = 16x32 B-tile = 64 lanes x 16B = 1024B) ----
constexpr int FB_PX   = 0;    // 7   KT=1
constexpr int FB_HE   = 7;    // 56  KT=8 (concat px|h)
constexpr int FB_EMU  = 63;   // 4   KT=4
constexpr int FB_ESIG = 67;   // 4
constexpr int FB_HP   = 71;   // 28  KT=4
constexpr int FB_PMU  = 99;   // 4
constexpr int FB_PSIG = 103;  // 4
constexpr int FB_PZ   = 107;  // 7   KT=1
constexpr int FB_HD1  = 114;  // 56  KT=8 (concat pz|h)
constexpr int FB_HD2  = 170;  // 28  KT=4
constexpr int FB_PRB  = 198;  // 8   KT=4 (Nt=2)
constexpr int FB_GIR  = 206;  // 56  KT=8 (concat pz|px)
constexpr int FB_GIU  = 262;  // 56
constexpr int FB_GIN  = 318;  // 56
constexpr int FB_GHR  = 374;  // 28  KT=4
constexpr int FB_GHU  = 402;  // 28
constexpr int FB_GHN  = 430;  // 28
constexpr int NFRAG   = 458;  // 469 KB in d_ws

struct Params {
  const float *x,*eps,*Wpx,*bpx,*Wpz,*bpz,*Wp1,*bp1,*Wp_mu,*bp_mu,*Wp_sig,*bp_sig,
              *We1,*be1,*We_mu,*be_mu,*We_sig,*be_sig,*Wd1,*bd1,*Wd2,*bd2,*Wd3,*bd3,
              *Wih,*Whh,*bih,*bhh;
  float *out;
};

DEVFN float frcp(float x){ return __builtin_amdgcn_rcpf(x); }
DEVFN float fsigmoid(float v){ return frcp(1.f + __expf(-v)); }
DEVFN float ftanh(float v){
  float t = __expf(-2.f*fabsf(v));           // (0,1], no overflow
  float r = (1.f - t) * frcp(1.f + t);
  return copysignf(r, v);
}
DEVFN float fsoftplus(float v){
  float sp = (v > 15.f) ? v : __logf(1.f + __expf(v));
  return fmaxf(sp, 1e-6f);                   // log/rcp safety in KL tail
}

DEVFN f32x4 MFMA(bf16x8 a, bf16x8 b, f32x4 c){
  return __builtin_amdgcn_mfma_f32_16x16x32_bf16(a, b, c, 0, 0, 0);
}

// ---------------- weight prep: fp32 -> bf16 B-fragments, biases folded into K-pad slot ----------------
__global__ void prep_kernel(Params P, __bf16* FRW)
{
  const int f = blockIdx.x, l = threadIdx.x;
  const int bases[18] = {FB_PX,FB_HE,FB_EMU,FB_ESIG,FB_HP,FB_PMU,FB_PSIG,FB_PZ,FB_HD1,
                         FB_HD2,FB_PRB,FB_GIR,FB_GIU,FB_GIN,FB_GHR,FB_GHU,FB_GHN,NFRAG};
  int li = 0;
  while (f >= bases[li+1]) ++li;

  const float* W; const float* Bv; int KT, N, roff, wstr, vK, mode;
  switch (li) {
    case 0:  W=P.Wpx;    Bv=P.bpx;    KT=1; N=100; roff=0;   wstr=28;  vK=28;  mode=0; break;
    case 1:  W=P.We1;    Bv=P.be1;    KT=8; N=100; roff=0;   wstr=200; vK=100; mode=1; break;
    case 2:  W=P.We_mu;  Bv=P.be_mu;  KT=4; N=16;  roff=0;   wstr=100; vK=100; mode=0; break;
    case 3:  W=P.We_sig; Bv=P.be_sig; KT=4; N=16;  roff=0;   wstr=100; vK=100; mode=0; break;
    case 4:  W=P.Wp1;    Bv=P.bp1;    KT=4; N=100; roff=0;   wstr=100; vK=100; mode=0; break;
    case 5:  W=P.Wp_mu;  Bv=P.bp_mu;  KT=4; N=16;  roff=0;   wstr=100; vK=100; mode=0; break;
    case 6:  W=P.Wp_sig; Bv=P.bp_sig; KT=4; N=16;  roff=0;   wstr=100; vK=100; mode=0; break;
    case 7:  W=P.Wpz;    Bv=P.bpz;    KT=1; N=100; roff=0;   wstr=16;  vK=16;  mode=0; break;
    case 8:  W=P.Wd1;    Bv=P.bd1;    KT=8; N=100; roff=0;   wstr=200; vK=100; mode=1; break;
    case 9:  W=P.Wd2;    Bv=P.bd2;    KT=4; N=100; roff=0;   wstr=100; vK=100; mode=0; break;
    case 10: W=P.Wd3;    Bv=P.bd3;    KT=4; N=28;  roff=0;   wstr=100; vK=100; mode=0; break;
    case 11: W=P.Wih;    Bv=P.bih;    KT=8; N=100; roff=0;   wstr=200; vK=100; mode=1; break;
    case 12: W=P.Wih;    Bv=P.bih;    KT=8; N=100; roff=100; wstr=200; vK=100; mode=1; break;
    case 13: W=P.Wih;    Bv=P.bih;    KT=8; N=100; roff=200; wstr=200; vK=100; mode=1; break;
    case 14: W=P.Whh;    Bv=P.bhh;    KT=4; N=100; roff=0;   wstr=100; vK=100; mode=0; break;
    case 15: W=P.Whh;    Bv=P.bhh;    KT=4; N=100; roff=100; wstr=100; vK=100; mode=0; break;
    default: W=P.Whh;    Bv=P.bhh;    KT=4; N=100; roff=200; wstr=100; vK=100; mode=0; break;
  }
  const int idx = f - bases[li];
  const int nt = idx / KT, kc = idx % KT;
  const int n  = nt*16 + (l & 15);

  bf16x8 v;
  #pragma unroll
  for (int j = 0; j < 8; ++j) {
    int kk  = (mode ? (kc & 3) : kc)*32 + ((l >> 4)*8) + j;
    float w = 0.f;
    if (n < N) {
      if (mode == 0) {
        if (kk < vK)       w = W[(size_t)(roff + n)*wstr + kk];
        else if (kk == vK) w = Bv[roff + n];                      // bias in K-pad slot
      } else {
        int col = (kc < 4 ? 0 : 100) + kk;
        if (kk < 100)                    w = W[(size_t)(roff + n)*wstr + col];
        else if (kc < 4 && kk == 100)    w = Bv[roff + n];        // bias in segment-0 pad slot
      }
    }
    v[j] = (__bf16)w;
  }
  *((bf16x8*)FRW + (size_t)f*64 + l) = v;
}

// ---------------- main kernel helpers (two M-halves share every weight-fragment load) ----------------
template<int NC>
DEVFN void load_afrags2(bf16x8 (&af)[2][NC], const __bf16* A, int stride, int lane)
{
  #pragma unroll
  for (int mh = 0; mh < 2; ++mh) {
    const __bf16* p = A + (size_t)((lane & 15) + mh*16)*stride + ((lane >> 4)*8);
    #pragma unroll
    for (int kc = 0; kc < NC; ++kc) af[mh][kc] = *(const bf16x8*)(p + kc*32);
  }
}

// volatile single-fragment LDS read: cannot be hoisted/CSE'd -> transient 4-VGPR lifetime.
// Used in the GRU loop to cap register pressure (the R3..R6 29MB scratch spill).
DEVFN bf16x8 vload_frag(const __bf16* A, int stride, int mh, int kc, int lane)
{
  const __bf16* p = A + (size_t)((lane & 15) + mh*16)*stride + ((lane >> 4)*8) + kc*32;
  return *(const volatile bf16x8*)p;
}

// H-output layer, both M-halves: one weight load -> two MFMAs
template<int KT>
DEVFN void layerH2(const bf16x8 (&af)[2][KT], const bf16x8* FRbase, __bf16* dst, int sw, int step, int lane)
{
  for (int nt = sw; nt < 7; nt += step) {
    f32x4 ac0 = {0.f,0.f,0.f,0.f}, ac1 = {0.f,0.f,0.f,0.f};
    const bf16x8* wf = FRbase + (size_t)nt*KT*64 + lane;
    #pragma unroll
    for (int kc = 0; kc < KT; ++kc) {
      bf16x8 w = wf[kc*64];
      ac0 = MFMA(af[0][kc], w, ac0);
      ac1 = MFMA(af[1][kc], w, ac1);
    }
    const int col = nt*16 + (lane & 15);
    if (col < H) {
      const int rbase = (lane >> 4)*4;
      #pragma unroll
      for (int r = 0; r < 4; ++r) {
        dst[(size_t)(rbase + r)*ST + col]      = (__bf16)fmaxf(ac0[r], 0.f);
        dst[(size_t)(16 + rbase + r)*ST + col] = (__bf16)fmaxf(ac1[r], 0.f);
      }
    }
  }
}

// K-concat single-tile, both M-halves
DEVFN void layerHcat2_1(const bf16x8 (&b0)[2][4], const bf16x8 (&b1)[2][4], const bf16x8* FRbase,
                        __bf16* dst, int nt, int lane)
{
  f32x4 ac0 = {0.f,0.f,0.f,0.f}, ac1 = {0.f,0.f,0.f,0.f};
  const bf16x8* wf = FRbase + (size_t)nt*8*64 + lane;
  #pragma unroll
  for (int kc = 0; kc < 4; ++kc) {
    bf16x8 w = wf[kc*64];
    ac0 = MFMA(b0[0][kc], w, ac0);
    ac1 = MFMA(b0[1][kc], w, ac1);
  }
  #pragma unroll
  for (int kc = 0; kc < 4; ++kc) {
    bf16x8 w = wf[(4+kc)*64];
    ac0 = MFMA(b1[0][kc], w, ac0);
    ac1 = MFMA(b1[1][kc], w, ac1);
  }
  const int col = nt*16 + (lane & 15);
  if (col < H) {
    const int rbase = (lane >> 4)*4;
    #pragma unroll
    for (int r = 0; r < 4; ++r) {
      dst[(size_t)(rbase + r)*ST + col]      = (__bf16)fmaxf(ac0[r], 0.f);
      dst[(size_t)(16 + rbase + r)*ST + col] = (__bf16)fmaxf(ac1[r], 0.f);
    }
  }
}

template<int KT>
DEVFN void head4x2(const bf16x8 (&af)[2][KT], const bf16x8* FRbase, int lane, f32x4& o0, f32x4& o1)
{
  f32x4 ac0 = {0.f,0.f,0.f,0.f}, ac1 = {0.f,0.f,0.f,0.f};
  #pragma unroll
  for (int kc = 0; kc < KT; ++kc) {
    bf16x8 w = FRbase[kc*64 + lane];
    ac0 = MFMA(af[0][kc], w, ac0);
    ac1 = MFMA(af[1][kc], w, ac1);
  }
  o0 = ac0; o1 = ac1;
}

// single-M head (P7 quadrant)
template<int KT>
DEVFN f32x4 head4(const bf16x8 (&af)[KT], const bf16x8* FRbase, int lane)
{
  f32x4 acc = {0.f,0.f,0.f,0.f};
  #pragma unroll
  for (int kc = 0; kc < KT; ++kc) acc = MFMA(af[kc], FRbase[kc*64 + lane], acc);
  return acc;
}

// launch_bounds MUST stay (NTH,2): the allocator always squeezes arch regs to the
// min-waves target: (256,4)->64 arch [R1 spill], (256,3)->84 arch [R8 spill],
// (256,2)->128 arch [no spill]. 8 waves/CU is where grid cap and reg cap meet.
// NO accumulators carried across barriers (R4: 313MB spill). P5 liveness capped via
// scoped hd1 + volatile per-kc A-frag reloads (R7). Indices scalarized (R9).
// R10: P3 de-dup — heads were computed by ALL 4 waves (96 redundant MFMAs + 4x z-VALU
// per block/step) to avoid a barrier. Now wave0 = enc heads + z (holds em,es in regs),
// wave1 = prior heads; (em,es,pm,ps) go through sHE (f32 LDS); KL is deferred to P5
// where a barrier already exists. Cost: +1 barrier (B3), measured ~neutral in R5/R6.
__global__ __launch_bounds__(NTH, 2) void vrnn_kernel(Params P, const __bf16* FRW)
{
  __shared__ alignas(16) __bf16 sPXb[2][HBUF];
  __shared__ alignas(16) __bf16 sPZ[HBUF];
  __shared__ alignas(16) __bf16 sA [HBUF];   // he -> hd1
  __shared__ alignas(16) __bf16 sBb[2][HBUF];// hp -> hd2
  __shared__ alignas(16) __bf16 sH0[HBUF];   // h double-buffer
  __shared__ alignas(16) __bf16 sH1[HBUF];
  __shared__ alignas(16) __bf16 sZ [ROWS*XST];
  __shared__ float sHE[4*ROWS*HEST];         // head exchange: em, es, pm, ps (f32)
  __shared__ float sred[8];

  const bf16x8* FR = (const bf16x8*)FRW;
  const int tid  = threadIdx.x;
  const int lane = tid & 63;
  const int uwv  = __builtin_amdgcn_readfirstlane(tid >> 6);   // wave id in SGPR (R9)
  const int gr0  = blockIdx.x * ROWS;

  // zero-init ALL LDS, then plant bias-activation 1.0 at the K-pad column.
  for (int i = tid; i < HBUF; i += NTH) {
    sPXb[0][i]=(__bf16)0.f; sPXb[1][i]=(__bf16)0.f; sPZ[i]=(__bf16)0.f; sA[i]=(__bf16)0.f;
    sBb[0][i]=(__bf16)0.f; sBb[1][i]=(__bf16)0.f; sH0[i]=(__bf16)0.f; sH1[i]=(__bf16)0.f;
  }
  for (int i = tid; i < ROWS*XST; i += NTH) sZ[i]=(__bf16)0.f;
  __syncthreads();
  if (tid < ROWS) {
    sPXb[0][tid*ST+100]=(__bf16)1.f; sPXb[1][tid*ST+100]=(__bf16)1.f;
    sPZ[tid*ST+100]=(__bf16)1.f; sA[tid*ST+100]=(__bf16)1.f;
    sBb[0][tid*ST+100]=(__bf16)1.f; sBb[1][tid*ST+100]=(__bf16)1.f;
    sH0[tid*ST+100]=(__bf16)1.f; sH1[tid*ST+100]=(__bf16)1.f;
    sZ[tid*XST+16]=(__bf16)1.f;
  }
  __syncthreads();

  float kl = 0.f, nll = 0.f;

  for (int t = 0; t < T; ++t) {
    __bf16* sHo = (t & 1) ? sH1 : sH0;   // h from previous step (t=0 reads zeroed sH0)
    __bf16* sHn = (t & 1) ? sH0 : sH1;   // h for next step
    __bf16* sPX = sPXb[t & 1];
    __bf16* sB  = sBb [t & 1];

    // ---- P1: px = relu(x Wpx^T + b) (x A-frags from global, bias-one at k=28) ; hp -> sB
    {
      bf16x8 ax[2][1];
      #pragma unroll
      for (int mh = 0; mh < 2; ++mh) {
        const float* xr = P.x + ((size_t)t*B + gr0 + mh*16 + (lane & 15))*X + (lane >> 4)*8;
        float4 fa = *(const float4*)xr;
        float4 fb = make_float4(0.f,0.f,0.f,0.f);
        if ((lane >> 4) < 3) fb = *(const float4*)(xr + 4);
        bf16x8 a;
        a[0]=(__bf16)fa.x; a[1]=(__bf16)fa.y; a[2]=(__bf16)fa.z; a[3]=(__bf16)fa.w;
        a[4]=(__bf16)fb.x; a[5]=(__bf16)fb.y; a[6]=(__bf16)fb.z; a[7]=(__bf16)fb.w;
        if ((lane >> 4) == 3) a[4] = (__bf16)1.f;    // k=28 bias slot
        ax[mh][0] = a;
      }
      layerH2<1>(ax, FR + (size_t)FB_PX*64, sPX, uwv, 4, lane);
      bf16x8 ah[2][4]; load_afrags2(ah, sHo, ST, lane);
      layerH2<4>(ah, FR + (size_t)FB_HP*64, sB, (uwv + 1) & 3, 4, lane); // offset balances wave3's 1-tile px
    }
    __syncthreads();   // B1

    // ---- P2: he = relu([px|h] We1^T + b) -> sA
    {
      bf16x8 a0[2][4]; load_afrags2(a0, sPX, ST, lane);
      bf16x8 a1[2][4]; load_afrags2(a1, sHo, ST, lane);
      for (int nt = uwv; nt < 7; nt += 4)
        layerHcat2_1(a0, a1, FR + (size_t)FB_HE*64, sA, nt, lane);
    }
    __syncthreads();   // B2

    // ---- P3 (de-dup, R10): wave0 = emu+esig + z (all rows) + (em,es)->sHE;
    //      wave1 = pmu+psig + (pm,ps)->sHE; waves 2,3 pass through to B3.
    if (uwv == 0) {
      bf16x8 a1[2][4]; load_afrags2(a1, sA, ST, lane);
      f32x4 emu[2], esg[2];
      head4x2(a1, FR + (size_t)FB_EMU*64,  lane, emu[0], emu[1]);
      head4x2(a1, FR + (size_t)FB_ESIG*64, lane, esg[0], esg[1]);
      const int zi = lane & 15;
      const int rbase = (lane >> 4)*4;
      #pragma unroll
      for (int mh = 0; mh < 2; ++mh) {
        #pragma unroll
        for (int r = 0; r < 4; ++r) {
          const int row = mh*16 + rbase + r;
          float em = emu[mh][r];
          float es = fsoftplus(esg[mh][r]);
          float ev = P.eps[((size_t)t*B + gr0 + row)*Z + zi];
          sZ[row*XST + zi] = (__bf16)(em + __builtin_amdgcn_sqrtf(es)*ev);
          sHE[0*ROWS*HEST + row*HEST + zi] = em;
          sHE[1*ROWS*HEST + row*HEST + zi] = es;
        }
      }
    } else if (uwv == 1) {
      bf16x8 a2[2][4]; load_afrags2(a2, sB, ST, lane);
      f32x4 pmu[2], psg[2];
      head4x2(a2, FR + (size_t)FB_PMU*64,  lane, pmu[0], pmu[1]);
      head4x2(a2, FR + (size_t)FB_PSIG*64, lane, psg[0], psg[1]);
      const int zi = lane & 15;
      const int rbase = (lane >> 4)*4;
      #pragma unroll
      for (int mh = 0; mh < 2; ++mh) {
        #pragma unroll
        for (int r = 0; r < 4; ++r) {
          const int row = mh*16 + rbase + r;
          sHE[2*ROWS*HEST + row*HEST + zi] = pmu[mh][r];
          sHE[3*ROWS*HEST + row*HEST + zi] = fsoftplus(psg[mh][r]) + KEPS;
        }
      }
    }
    __syncthreads();   // B3 (new: sZ/sHE now cooperatively produced)

    // ---- P4: pz = relu(z Wpz^T + b) -> sPZ  (bias-one at z col 16)
    {
      bf16x8 az[2][1];
      #pragma unroll
      for (int mh = 0; mh < 2; ++mh)
        az[mh][0] = *(const bf16x8*)(sZ + (size_t)((lane & 15) + mh*16)*XST + (lane >> 4)*8);
      layerH2<1>(az, FR + (size_t)FB_PZ*64, sPZ, uwv, 4, lane);
    }
    __syncthreads();   // B4

    // ---- P5: deferred KL (reads sHE; rows partitioned by wave) ; hd1 -> sA ;
    //      fused GRU sHo -> sHn. Liveness-capped per R7.
    {
      {  // KL: wave w covers rows [8w, 8w+8); each thread does 2 (row, zi) items.
        const int zi = lane & 15;
        const int r0 = 8*uwv + (lane >> 4);
        #pragma unroll
        for (int rr = 0; rr < 2; ++rr) {
          const int row = r0 + rr*4;
          float em = sHE[0*ROWS*HEST + row*HEST + zi];
          float es = sHE[1*ROWS*HEST + row*HEST + zi];
          float pm = sHE[2*ROWS*HEST + row*HEST + zi];
          float ps = sHE[3*ROWS*HEST + row*HEST + zi];
          float dm = em - pm;
          float rps = frcp(ps);
          kl += 0.5f*(2.f*__logf(ps*frcp(es)) + (es*es + dm*dm)*(rps*rps) - 1.f);
        }
      }

      {  // hd1 sub-phase: frags die here
        bf16x8 apz[2][4]; load_afrags2(apz, sPZ, ST, lane);
        bf16x8 ah [2][4]; load_afrags2(ah,  sHo, ST, lane);
        if (uwv == 3) {
          for (int nt = 0; nt < 7; nt += 2)
            layerHcat2_1(apz, ah, FR + (size_t)FB_HD1*64, sA, nt, lane);
        } else {
          layerHcat2_1(apz, ah, FR + (size_t)FB_HD1*64, sA, 2*uwv + 1, lane);
        }
      }

      #pragma unroll 1
      for (int c = uwv; c < 7; c += 4) {
        const f32x4 z4 = {0.f,0.f,0.f,0.f};
        f32x4 gr[2]={z4,z4}, gu[2]={z4,z4}, gn[2]={z4,z4};
        const bf16x8* wr = FR + (size_t)(FB_GIR + c*8)*64 + lane;
        const bf16x8* wu = FR + (size_t)(FB_GIU + c*8)*64 + lane;
        const bf16x8* wn = FR + (size_t)(FB_GIN + c*8)*64 + lane;
        #pragma unroll
        for (int kc = 0; kc < 4; ++kc) {        // gi part 1: pz (bih folded here)
          bf16x8 a0 = vload_frag(sPZ, ST, 0, kc, lane);
          bf16x8 a1 = vload_frag(sPZ, ST, 1, kc, lane);
          bf16x8 wR = wr[kc*64], wU = wu[kc*64], wN = wn[kc*64];
          gr[0] = MFMA(a0, wR, gr[0]); gu[0] = MFMA(a0, wU, gu[0]); gn[0] = MFMA(a0, wN, gn[0]);
          gr[1] = MFMA(a1, wR, gr[1]); gu[1] = MFMA(a1, wU, gu[1]); gn[1] = MFMA(a1, wN, gn[1]);
        }
        #pragma unroll
        for (int kc = 0; kc < 4; ++kc) {        // gi part 2: px
          bf16x8 a0 = vload_frag(sPX, ST, 0, kc, lane);
          bf16x8 a1 = vload_frag(sPX, ST, 1, kc, lane);
          bf16x8 wR = wr[(4+kc)*64], wU = wu[(4+kc)*64], wN = wn[(4+kc)*64];
          gr[0] = MFMA(a0, wR, gr[0]); gu[0] = MFMA(a0, wU, gu[0]); gn[0] = MFMA(a0, wN, gn[0]);
          gr[1] = MFMA(a1, wR, gr[1]); gu[1] = MFMA(a1, wU, gu[1]); gn[1] = MFMA(a1, wN, gn[1]);
        }
        f32x4 hr[2]={z4,z4}, hu[2]={z4,z4}, hn[2]={z4,z4};
        const bf16x8* vr = FR + (size_t)(FB_GHR + c*4)*64 + lane;
        const bf16x8* vu = FR + (size_t)(FB_GHU + c*4)*64 + lane;
        const bf16x8* vn = FR + (size_t)(FB_GHN + c*4)*64 + lane;
        #pragma unroll
        for (int kc = 0; kc < 4; ++kc) {        // gh: h (bhh folded here)
          bf16x8 a0 = vload_frag(sHo, ST, 0, kc, lane);
          bf16x8 a1 = vload_frag(sHo, ST, 1, kc, lane);
          bf16x8 wR = vr[kc*64], wU = vu[kc*64], wN = vn[kc*64];
          hr[0] = MFMA(a0, wR, hr[0]); hu[0] = MFMA(a0, wU, hu[0]); hn[0] = MFMA(a0, wN, hn[0]);
          hr[1] = MFMA(a1, wR, hr[1]); hu[1] = MFMA(a1, wU, hu[1]); hn[1] = MFMA(a1, wN, hn[1]);
        }
        const int n = c*16 + (lane & 15);
        if (n < H) {
          const int rbase = (lane >> 4)*4;
          #pragma unroll
          for (int mh = 0; mh < 2; ++mh) {
            #pragma unroll
            for (int r = 0; r < 4; ++r) {
              float rr = fsigmoid(gr[mh][r] + hr[mh][r]);
              float uu = fsigmoid(gu[mh][r] + hu[mh][r]);
              float nn = ftanh(gn[mh][r] + rr*hn[mh][r]);
              const size_t off = (size_t)(mh*16 + rbase + r)*ST + n;
              float ho = (float)sHo[off];
              sHn[off] = (__bf16)((1.f-uu)*nn + uu*ho);
            }
          }
        }
      }
    }
    __syncthreads();   // B5

    // ---- P6: hd2 = relu(hd1 Wd2^T + b) : sA -> sB
    {
      bf16x8 af[2][4]; load_afrags2(af, sA, ST, lane);
      layerH2<4>(af, FR + (size_t)FB_HD2*64, sB, uwv, 4, lane);
    }
    __syncthreads();   // B6

    // ---- P7: logits v = hd2 Wd3^T + b ; NLL via log-sigmoid identity
    //      quadrant split: N-tile = uwv&1, M-half = uwv>>1 (no redundancy)
    //      NO trailing barrier: sPX/sB are t-parity double-buffered; any wave entering
    //      P1(t+1) already passed B6(t) => sHn complete and opposite-parity writes only.
    {
      const int pt = uwv & 1;
      const int mh = uwv >> 1;
      bf16x8 af[4];
      const __bf16* p = sB + (size_t)((lane & 15) + mh*16)*ST + ((lane >> 4)*8);
      #pragma unroll
      for (int kc = 0; kc < 4; ++kc) af[kc] = *(const bf16x8*)(p + kc*32);
      f32x4 acc = head4(af, FR + (size_t)(FB_PRB + pt*4)*64, lane);
      const int n = pt*16 + (lane & 15);
      if (n < X) {
        const int rbase = (lane >> 4)*4;
        #pragma unroll
        for (int r = 0; r < 4; ++r) {
          float v  = acc[r];
          float xv = P.x[((size_t)t*B + gr0 + mh*16 + rbase + r)*X + n];
          nll += fmaxf(-v, 0.f) + __logf(1.f + __expf(-fabsf(v))) + (1.f - xv)*v;
        }
      }
    }
  } // t

  __syncthreads();   // seal last step before reduction

  // ---- reduce kl/nll: wave shuffle -> LDS -> one atomicAdd per block
  for (int off = 32; off > 0; off >>= 1) {
    kl  += __shfl_down(kl,  off);
    nll += __shfl_down(nll, off);
  }
  if (lane == 0) { sred[uwv] = kl; sred[4 + uwv] = nll; }
  __syncthreads();
  if (tid == 0) {
    atomicAdd(&P.out[0], (sred[0] + sred[1] + sred[2] + sred[3]) * (1.f/(float)B));
    atomicAdd(&P.out[1], (sred[4] + sred[5] + sred[6] + sred[7]) * (1.f/(float)B));
  }
}

} // namespace

extern "C" void kernel_launch(void* const* d_in, const int* in_sizes, int n_in,
                              void* d_out, int out_size, void* d_ws, size_t ws_size,
                              hipStream_t stream)
{
  Params p;
  const float* const* f = (const float* const*)d_in;
  p.x=f[0];    p.eps=f[1];
  p.Wpx=f[2];  p.bpx=f[3];   p.Wpz=f[4];   p.bpz=f[5];
  p.Wp1=f[6];  p.bp1=f[7];   p.Wp_mu=f[8]; p.bp_mu=f[9];
  p.Wp_sig=f[10]; p.bp_sig=f[11];
  p.We1=f[12]; p.be1=f[13];  p.We_mu=f[14]; p.be_mu=f[15];
  p.We_sig=f[16]; p.be_sig=f[17];
  p.Wd1=f[18]; p.bd1=f[19];  p.Wd2=f[20];  p.bd2=f[21];
  p.Wd3=f[22]; p.bd3=f[23];
  p.Wih=f[24]; p.Whh=f[25];  p.bih=f[26];  p.bhh=f[27];
  p.out = (float*)d_out;

  hipMemsetAsync(d_out, 0, 2*sizeof(float), stream);
  prep_kernel<<<dim3(NFRAG), dim3(64), 0, stream>>>(p, (__bf16*)d_ws);
  vrnn_kernel<<<dim3(B/ROWS), dim3(NTH), 0, stream>>>(p, (const __bf16*)d_ws);
}